// Round 3
// baseline (176.674 us; speedup 1.0000x reference)
//
#include <hip/hip_runtime.h>
#include <hip/hip_bf16.h>

// Problem constants (match the reference).
#define NG 32768
#define MP 8192
#define BG_VAL (-1.0f)
#define MAX_SCALE 0.02f

// 0.5 * log2(e): folded (negated) into the precomputed polynomial coefficients
// so the inner loop is alpha = w * exp2(poly(p)) with zero extra negates/muls.
#define HALF_LOG2E 0.72134752044448170f

#define BLK 256               // threads per block
#define PPT 2                 // points per thread
#define PT_PER_BLK (BLK * PPT)        // 512 points per block
#define PT_TILES (MP / PT_PER_BLK)    // 16

// ---------------------------------------------------------------------------
// Kernel 1: per-gaussian precompute.
// The Mahalanobis quadratic is expanded in the point p directly:
//   -c*(p-mu)^T G (p-mu) = A.p^2-terms + cross-terms + linear + const
// Layout per gaussian (3x float4):
//   A0 = (-c*G00, -c*G11, -c*G22, -2c*G01)
//   A1 = (-2c*G02, -2c*G12, h0, h1)        h = 2c * G mu
//   A2 = (h2, k0, w, w*v)                  k0 = -c * mu^T G mu = -(h.mu)/2
// Inner loop: q = 9 fmas over {p00,p11,p22,p01,p02,p12,p0,p1,p2}, e = exp2(q).
// ---------------------------------------------------------------------------
__global__ __launch_bounds__(256) void vegs_precompute(
    const float* __restrict__ xyz,
    const float* __restrict__ weight_raw,
    const float* __restrict__ scaling_raw,
    const float* __restrict__ rotation_raw,
    const float* __restrict__ values_raw,
    float4* __restrict__ gp)
{
    int n = blockIdx.x * blockDim.x + threadIdx.x;
    if (n >= NG) return;

    // s = exp(scaling_raw), soft-clamped to MAX_SCALE
    float s0 = __expf(scaling_raw[n * 3 + 0]);
    float s1 = __expf(scaling_raw[n * 3 + 1]);
    float s2 = __expf(scaling_raw[n * 3 + 2]);
    float r = sqrtf(s0 * s0 + s1 * s1 + s2 * s2) + 1e-8f;
    float rs = MAX_SCALE * tanhf(r * (1.0f / MAX_SCALE));
    float k = rs / r;
    s0 *= k; s1 *= k; s2 *= k;

    float i0 = 1.0f / (s0 * s0);
    float i1 = 1.0f / (s1 * s1);
    float i2 = 1.0f / (s2 * s2);

    // normalized quaternion
    float qw = rotation_raw[n * 4 + 0];
    float qx = rotation_raw[n * 4 + 1];
    float qy = rotation_raw[n * 4 + 2];
    float qz = rotation_raw[n * 4 + 3];
    float qn = sqrtf(qw * qw + qx * qx + qy * qy + qz * qz) + 1e-12f;
    float inv_qn = 1.0f / qn;
    qw *= inv_qn; qx *= inv_qn; qy *= inv_qn; qz *= inv_qn;

    // rotation matrix
    float r00 = 1.0f - 2.0f * (qy * qy + qz * qz);
    float r01 = 2.0f * (qx * qy - qw * qz);
    float r02 = 2.0f * (qx * qz + qw * qy);
    float r10 = 2.0f * (qx * qy + qw * qz);
    float r11 = 1.0f - 2.0f * (qx * qx + qz * qz);
    float r12 = 2.0f * (qy * qz - qw * qx);
    float r20 = 2.0f * (qx * qz - qw * qy);
    float r21 = 2.0f * (qy * qz + qw * qx);
    float r22 = 1.0f - 2.0f * (qx * qx + qy * qy);

    // inv_cov = R diag(1/s^2) R^T (symmetric)
    float G00 = r00 * r00 * i0 + r01 * r01 * i1 + r02 * r02 * i2;
    float G11 = r10 * r10 * i0 + r11 * r11 * i1 + r12 * r12 * i2;
    float G22 = r20 * r20 * i0 + r21 * r21 * i1 + r22 * r22 * i2;
    float G01 = r00 * r10 * i0 + r01 * r11 * i1 + r02 * r12 * i2;
    float G02 = r00 * r20 * i0 + r01 * r21 * i1 + r02 * r22 * i2;
    float G12 = r10 * r20 * i0 + r11 * r21 * i1 + r12 * r22 * i2;

    float w = 1.0f / (1.0f + __expf(-weight_raw[n]));
    float v = 1.0f / (1.0f + __expf(-values_raw[n]));

    float m0 = xyz[n * 3 + 0];
    float m1 = xyz[n * 3 + 1];
    float m2 = xyz[n * 3 + 2];

    const float c = HALF_LOG2E;
    // h = 2c * G mu
    float h0 = 2.0f * c * (G00 * m0 + G01 * m1 + G02 * m2);
    float h1 = 2.0f * c * (G01 * m0 + G11 * m1 + G12 * m2);
    float h2 = 2.0f * c * (G02 * m0 + G12 * m1 + G22 * m2);
    float k0 = -0.5f * (h0 * m0 + h1 * m1 + h2 * m2);

    gp[n * 3 + 0] = make_float4(-c * G00, -c * G11, -c * G22, -2.0f * c * G01);
    gp[n * 3 + 1] = make_float4(-2.0f * c * G02, -2.0f * c * G12, h0, h1);
    gp[n * 3 + 2] = make_float4(h2, k0, w, w * v);
}

// ---------------------------------------------------------------------------
// Kernel 2: main pairwise evaluation.
// grid = (PT_TILES, nchunk). Each block: 256 threads x 2 points = 512 points
// vs one chunk of CHUNK gaussians staged in LDS (uniform broadcast reads).
// Per pair: 9 fma (poly) + exp2 + 2 fma (accumulate). Writes (num,den).
// ---------------------------------------------------------------------------
template <int CHUNK>
__global__ __launch_bounds__(BLK, 8) void vegs_main(
    const float* __restrict__ x,
    const float4* __restrict__ gp,
    float2* __restrict__ partial)
{
    __shared__ float4 lds[CHUNK * 3];

    const int m0 = blockIdx.x * PT_PER_BLK + threadIdx.x;  // point A
    const int m1 = m0 + BLK;                               // point B
    const int c  = blockIdx.y;                             // chunk index

    const float4* __restrict__ src = gp + (size_t)c * CHUNK * 3;
    #pragma unroll
    for (int i = threadIdx.x; i < CHUNK * 3; i += BLK) lds[i] = src[i];

    // point monomials (p = (x+1)/2): {p^2 terms, cross, linear}
    float a0 = (x[m0 * 3 + 0] + 1.0f) * 0.5f;
    float a1 = (x[m0 * 3 + 1] + 1.0f) * 0.5f;
    float a2 = (x[m0 * 3 + 2] + 1.0f) * 0.5f;
    float b0 = (x[m1 * 3 + 0] + 1.0f) * 0.5f;
    float b1 = (x[m1 * 3 + 1] + 1.0f) * 0.5f;
    float b2 = (x[m1 * 3 + 2] + 1.0f) * 0.5f;
    float a00 = a0 * a0, a11 = a1 * a1, a22 = a2 * a2;
    float a01 = a0 * a1, a02 = a0 * a2, a12 = a1 * a2;
    float b00 = b0 * b0, b11 = b1 * b1, b22 = b2 * b2;
    float b01 = b0 * b1, b02 = b0 * b2, b12 = b1 * b2;

    __syncthreads();

    float numA = 0.0f, denA = 0.0f;
    float numB = 0.0f, denB = 0.0f;

    #pragma unroll 8
    for (int j = 0; j < CHUNK; ++j) {
        float4 A0 = lds[j * 3 + 0];
        float4 A1 = lds[j * 3 + 1];
        float4 A2 = lds[j * 3 + 2];

        // point A: q = k0 + sum coeff*monomial  (9 fmas)
        float qA = fmaf(A0.x, a00, A2.y);
        qA = fmaf(A0.y, a11, qA);
        qA = fmaf(A0.z, a22, qA);
        qA = fmaf(A0.w, a01, qA);
        qA = fmaf(A1.x, a02, qA);
        qA = fmaf(A1.y, a12, qA);
        qA = fmaf(A1.z, a0, qA);
        qA = fmaf(A1.w, a1, qA);
        qA = fmaf(A2.x, a2, qA);
        float eA = __builtin_amdgcn_exp2f(qA);
        denA = fmaf(A2.z, eA, denA);
        numA = fmaf(A2.w, eA, numA);

        // point B
        float qB = fmaf(A0.x, b00, A2.y);
        qB = fmaf(A0.y, b11, qB);
        qB = fmaf(A0.z, b22, qB);
        qB = fmaf(A0.w, b01, qB);
        qB = fmaf(A1.x, b02, qB);
        qB = fmaf(A1.y, b12, qB);
        qB = fmaf(A1.z, b0, qB);
        qB = fmaf(A1.w, b1, qB);
        qB = fmaf(A2.x, b2, qB);
        float eB = __builtin_amdgcn_exp2f(qB);
        denB = fmaf(A2.z, eB, denB);
        numB = fmaf(A2.w, eB, numB);
    }

    partial[(size_t)c * MP + m0] = make_float2(numA, denA);
    partial[(size_t)c * MP + m1] = make_float2(numB, denB);
}

// ---------------------------------------------------------------------------
// Kernel 3: reduce partials over chunks, apply background select.
// ---------------------------------------------------------------------------
__global__ __launch_bounds__(256) void vegs_reduce(
    const float2* __restrict__ partial,
    float* __restrict__ out,
    int nchunk)
{
    int m = blockIdx.x * blockDim.x + threadIdx.x;
    if (m >= MP) return;
    float num = 0.0f, den = 0.0f;
    for (int c = 0; c < nchunk; ++c) {
        float2 p = partial[(size_t)c * MP + m];
        num += p.x;
        den += p.y;
    }
    out[m] = (den > 1e-8f) ? num : BG_VAL;
}

extern "C" void kernel_launch(void* const* d_in, const int* in_sizes, int n_in,
                              void* d_out, int out_size, void* d_ws, size_t ws_size,
                              hipStream_t stream) {
    const float* x            = (const float*)d_in[0];
    const float* xyz          = (const float*)d_in[1];
    const float* weight_raw   = (const float*)d_in[2];
    const float* scaling_raw  = (const float*)d_in[3];
    const float* rotation_raw = (const float*)d_in[4];
    const float* values_raw   = (const float*)d_in[5];
    float* out = (float*)d_out;

    char* ws = (char*)d_ws;
    float4* gp = (float4*)ws;                                  // 1.5 MB
    float2* partial = (float2*)(ws + (size_t)NG * 3 * sizeof(float4));

    vegs_precompute<<<NG / 256, 256, 0, stream>>>(
        xyz, weight_raw, scaling_raw, rotation_raw, values_raw, gp);

    // Prefer CHUNK=256 (128 chunks -> 2048 blocks -> full static occupancy);
    // fall back to CHUNK=512 if the workspace can't hold the larger partials.
    size_t need256 = (size_t)NG * 3 * sizeof(float4)
                   + (size_t)(NG / 256) * MP * sizeof(float2);   // ~10 MB
    if (ws_size >= need256) {
        const int nchunk = NG / 256;   // 128
        dim3 grid(PT_TILES, nchunk);
        vegs_main<256><<<grid, BLK, 0, stream>>>(x, gp, partial);
        vegs_reduce<<<MP / 256, 256, 0, stream>>>(partial, out, nchunk);
    } else {
        const int nchunk = NG / 512;   // 64
        dim3 grid(PT_TILES, nchunk);
        vegs_main<512><<<grid, BLK, 0, stream>>>(x, gp, partial);
        vegs_reduce<<<MP / 256, 256, 0, stream>>>(partial, out, nchunk);
    }
}

// Round 4
// 174.110 us; speedup vs baseline: 1.0147x; 1.0147x over previous
//
#include <hip/hip_runtime.h>
#include <hip/hip_bf16.h>

// Problem constants (match the reference).
#define NG 32768
#define MP 8192
#define BG_VAL (-1.0f)
#define MAX_SCALE 0.02f

// 0.5 * log2(e): folded (negated) into the precomputed polynomial coefficients
// so the inner loop is alpha = w * exp2(poly(p)) with zero extra negates/muls.
#define HALF_LOG2E 0.72134752044448170f

#define BLK 256               // threads per block
#define PPT 2                 // points per thread
#define PT_PER_BLK (BLK * PPT)        // 512 points per block
#define PT_TILES (MP / PT_PER_BLK)    // 16

// ---------------------------------------------------------------------------
// Kernel 1: per-gaussian precompute.
// Mahalanobis quadratic expanded in the point p directly:
//   -c*(p-mu)^T G (p-mu) = quadratic + cross + linear + const   (c=0.5*log2e)
// Layout per gaussian (3x float4):
//   A0 = (-c*G00, -c*G11, -c*G22, -2c*G01)
//   A1 = (-2c*G02, -2c*G12, h0, h1)        h = 2c * G mu
//   A2 = (h2, k0, w, w*v)                  k0 = -(h.mu)/2
// ---------------------------------------------------------------------------
__global__ __launch_bounds__(256) void vegs_precompute(
    const float* __restrict__ xyz,
    const float* __restrict__ weight_raw,
    const float* __restrict__ scaling_raw,
    const float* __restrict__ rotation_raw,
    const float* __restrict__ values_raw,
    float4* __restrict__ gp)
{
    int n = blockIdx.x * blockDim.x + threadIdx.x;
    if (n >= NG) return;

    float s0 = __expf(scaling_raw[n * 3 + 0]);
    float s1 = __expf(scaling_raw[n * 3 + 1]);
    float s2 = __expf(scaling_raw[n * 3 + 2]);
    float r = sqrtf(s0 * s0 + s1 * s1 + s2 * s2) + 1e-8f;
    float rs = MAX_SCALE * tanhf(r * (1.0f / MAX_SCALE));
    float k = rs / r;
    s0 *= k; s1 *= k; s2 *= k;

    float i0 = 1.0f / (s0 * s0);
    float i1 = 1.0f / (s1 * s1);
    float i2 = 1.0f / (s2 * s2);

    float qw = rotation_raw[n * 4 + 0];
    float qx = rotation_raw[n * 4 + 1];
    float qy = rotation_raw[n * 4 + 2];
    float qz = rotation_raw[n * 4 + 3];
    float qn = sqrtf(qw * qw + qx * qx + qy * qy + qz * qz) + 1e-12f;
    float inv_qn = 1.0f / qn;
    qw *= inv_qn; qx *= inv_qn; qy *= inv_qn; qz *= inv_qn;

    float r00 = 1.0f - 2.0f * (qy * qy + qz * qz);
    float r01 = 2.0f * (qx * qy - qw * qz);
    float r02 = 2.0f * (qx * qz + qw * qy);
    float r10 = 2.0f * (qx * qy + qw * qz);
    float r11 = 1.0f - 2.0f * (qx * qx + qz * qz);
    float r12 = 2.0f * (qy * qz - qw * qx);
    float r20 = 2.0f * (qx * qz - qw * qy);
    float r21 = 2.0f * (qy * qz + qw * qx);
    float r22 = 1.0f - 2.0f * (qx * qx + qy * qy);

    float G00 = r00 * r00 * i0 + r01 * r01 * i1 + r02 * r02 * i2;
    float G11 = r10 * r10 * i0 + r11 * r11 * i1 + r12 * r12 * i2;
    float G22 = r20 * r20 * i0 + r21 * r21 * i1 + r22 * r22 * i2;
    float G01 = r00 * r10 * i0 + r01 * r11 * i1 + r02 * r12 * i2;
    float G02 = r00 * r20 * i0 + r01 * r21 * i1 + r02 * r22 * i2;
    float G12 = r10 * r20 * i0 + r11 * r21 * i1 + r12 * r22 * i2;

    float w = 1.0f / (1.0f + __expf(-weight_raw[n]));
    float v = 1.0f / (1.0f + __expf(-values_raw[n]));

    float m0 = xyz[n * 3 + 0];
    float m1 = xyz[n * 3 + 1];
    float m2 = xyz[n * 3 + 2];

    const float c = HALF_LOG2E;
    float h0 = 2.0f * c * (G00 * m0 + G01 * m1 + G02 * m2);
    float h1 = 2.0f * c * (G01 * m0 + G11 * m1 + G12 * m2);
    float h2 = 2.0f * c * (G02 * m0 + G12 * m1 + G22 * m2);
    float k0 = -0.5f * (h0 * m0 + h1 * m1 + h2 * m2);

    gp[n * 3 + 0] = make_float4(-c * G00, -c * G11, -c * G22, -2.0f * c * G01);
    gp[n * 3 + 1] = make_float4(-2.0f * c * G02, -2.0f * c * G12, h0, h1);
    gp[n * 3 + 2] = make_float4(h2, k0, w, w * v);
}

// ---------------------------------------------------------------------------
// Kernel 2: main pairwise evaluation — SGPR-broadcast coefficient path.
// grid = (PT_TILES, nchunk). The gaussian coefficients are loaded through a
// wave-UNIFORM address (loop index j + blockIdx.y only) from a const
// __restrict__ pointer, so they lower to s_load_dwordx4 into SGPRs (scalar
// cache resident: 12 KB/chunk). Every inner fma is then
// sgpr_coeff * vgpr_monomial + vgpr_acc — the legal 1-SGPR VALU form.
// No LDS, no __syncthreads, monomials stay resident in VGPRs.
// ---------------------------------------------------------------------------
template <int CHUNK>
__global__ __launch_bounds__(BLK, 4) void vegs_main(
    const float* __restrict__ x,
    const float4* __restrict__ gp,
    float2* __restrict__ partial)
{
    const int m0 = blockIdx.x * PT_PER_BLK + threadIdx.x;  // point A
    const int m1 = m0 + BLK;                               // point B
    const float4* __restrict__ src = gp + (size_t)blockIdx.y * (CHUNK * 3);

    // point monomials (p = (x+1)/2)
    float a0 = (x[m0 * 3 + 0] + 1.0f) * 0.5f;
    float a1 = (x[m0 * 3 + 1] + 1.0f) * 0.5f;
    float a2 = (x[m0 * 3 + 2] + 1.0f) * 0.5f;
    float b0 = (x[m1 * 3 + 0] + 1.0f) * 0.5f;
    float b1 = (x[m1 * 3 + 1] + 1.0f) * 0.5f;
    float b2 = (x[m1 * 3 + 2] + 1.0f) * 0.5f;
    float a00 = a0 * a0, a11 = a1 * a1, a22 = a2 * a2;
    float a01 = a0 * a1, a02 = a0 * a2, a12 = a1 * a2;
    float b00 = b0 * b0, b11 = b1 * b1, b22 = b2 * b2;
    float b01 = b0 * b1, b02 = b0 * b2, b12 = b1 * b2;

    float numA = 0.0f, denA = 0.0f;
    float numB = 0.0f, denB = 0.0f;

    #pragma unroll 4
    for (int j = 0; j < CHUNK; ++j) {
        float4 A0 = src[j * 3 + 0];
        float4 A1 = src[j * 3 + 1];
        float4 A2 = src[j * 3 + 2];

        float qA = fmaf(A0.x, a00, A2.y);
        qA = fmaf(A0.y, a11, qA);
        qA = fmaf(A0.z, a22, qA);
        qA = fmaf(A0.w, a01, qA);
        qA = fmaf(A1.x, a02, qA);
        qA = fmaf(A1.y, a12, qA);
        qA = fmaf(A1.z, a0, qA);
        qA = fmaf(A1.w, a1, qA);
        qA = fmaf(A2.x, a2, qA);
        float eA = __builtin_amdgcn_exp2f(qA);
        denA = fmaf(A2.z, eA, denA);
        numA = fmaf(A2.w, eA, numA);

        float qB = fmaf(A0.x, b00, A2.y);
        qB = fmaf(A0.y, b11, qB);
        qB = fmaf(A0.z, b22, qB);
        qB = fmaf(A0.w, b01, qB);
        qB = fmaf(A1.x, b02, qB);
        qB = fmaf(A1.y, b12, qB);
        qB = fmaf(A1.z, b0, qB);
        qB = fmaf(A1.w, b1, qB);
        qB = fmaf(A2.x, b2, qB);
        float eB = __builtin_amdgcn_exp2f(qB);
        denB = fmaf(A2.z, eB, denB);
        numB = fmaf(A2.w, eB, numB);
    }

    partial[(size_t)blockIdx.y * MP + m0] = make_float2(numA, denA);
    partial[(size_t)blockIdx.y * MP + m1] = make_float2(numB, denB);
}

// ---------------------------------------------------------------------------
// Kernel 3: parallel reduce. grid = MP/64 blocks x 256 threads.
// 4 threads per point (t>>6 = chunk-slice), coalesced 512B wave reads,
// LDS combine, background select.
// ---------------------------------------------------------------------------
template <int NCHUNK>
__global__ __launch_bounds__(256) void vegs_reduce(
    const float2* __restrict__ partial,
    float* __restrict__ out)
{
    __shared__ float2 red[256];
    const int t = threadIdx.x;
    const int m = blockIdx.x * 64 + (t & 63);
    const int s = t >> 6;                       // slice 0..3
    constexpr int PER = NCHUNK / 4;

    float num = 0.0f, den = 0.0f;
    #pragma unroll 8
    for (int k = 0; k < PER; ++k) {
        float2 p = partial[(size_t)(s * PER + k) * MP + m];
        num += p.x;
        den += p.y;
    }
    red[t] = make_float2(num, den);
    __syncthreads();
    if (t < 64) {
        float2 r0 = red[t], r1 = red[t + 64], r2 = red[t + 128], r3 = red[t + 192];
        float n = r0.x + r1.x + r2.x + r3.x;
        float d = r0.y + r1.y + r2.y + r3.y;
        out[m] = (d > 1e-8f) ? n : BG_VAL;
    }
}

extern "C" void kernel_launch(void* const* d_in, const int* in_sizes, int n_in,
                              void* d_out, int out_size, void* d_ws, size_t ws_size,
                              hipStream_t stream) {
    const float* x            = (const float*)d_in[0];
    const float* xyz          = (const float*)d_in[1];
    const float* weight_raw   = (const float*)d_in[2];
    const float* scaling_raw  = (const float*)d_in[3];
    const float* rotation_raw = (const float*)d_in[4];
    const float* values_raw   = (const float*)d_in[5];
    float* out = (float*)d_out;

    char* ws = (char*)d_ws;
    float4* gp = (float4*)ws;                                  // 1.5 MB
    float2* partial = (float2*)(ws + (size_t)NG * 3 * sizeof(float4));

    vegs_precompute<<<NG / 256, 256, 0, stream>>>(
        xyz, weight_raw, scaling_raw, rotation_raw, values_raw, gp);

    size_t need256 = (size_t)NG * 3 * sizeof(float4)
                   + (size_t)(NG / 256) * MP * sizeof(float2);   // ~9.9 MB
    if (ws_size >= need256) {
        dim3 grid(PT_TILES, NG / 256);                          // 16 x 128
        vegs_main<256><<<grid, BLK, 0, stream>>>(x, gp, partial);
        vegs_reduce<128><<<MP / 64, 256, 0, stream>>>(partial, out);
    } else {
        dim3 grid(PT_TILES, NG / 512);                          // 16 x 64
        vegs_main<512><<<grid, BLK, 0, stream>>>(x, gp, partial);
        vegs_reduce<64><<<MP / 64, 256, 0, stream>>>(partial, out);
    }
}

// Round 6
// 135.131 us; speedup vs baseline: 1.3074x; 1.2884x over previous
//
#include <hip/hip_runtime.h>

// Problem constants (match the reference).
#define NG 32768
#define MP 8192
#define BG_VAL (-1.0f)
#define MAX_SCALE 0.02f

#define HALF_LOG2E 0.72134752044448170f   // 0.5*log2(e)
#define LOG2E      1.44269504088896340f

#define BLK 256
#define PPT 4                          // points per thread
#define CHUNK 256                      // gaussians per chunk (= BLK: 1/thread in precompute phase)
#define NCHUNK (NG / CHUNK)            // 128
#define PT_PER_BLK (BLK * PPT)         // 1024
#define PT_TILES (MP / PT_PER_BLK)     // 8

typedef float f32x2 __attribute__((ext_vector_type(2)));
typedef float f32x4 __attribute__((ext_vector_type(4)));

__device__ __forceinline__ float fast_rcp(float x)  { return __builtin_amdgcn_rcpf(x); }
__device__ __forceinline__ float fast_exp2(float x) { return __builtin_amdgcn_exp2f(x); }
__device__ __forceinline__ float fast_exp(float x)  { return fast_exp2(x * LOG2E); }
__device__ __forceinline__ float fast_sigmoid(float x) { return fast_rcp(1.0f + fast_exp(-x)); }

// Packed dual-FP32 FMA (v_pk_fma_f32, full-rate on CDNA): d = c*m + d  /  d = c*m + a.
// Inline asm guarantees packing AND makes operands un-rematerializable.
#define PK_FMA(q, c, m)      asm("v_pk_fma_f32 %0, %1, %2, %0" : "+v"(q) : "v"(c), "v"(m))
#define PK_FMA3(d, c, m, a)  asm("v_pk_fma_f32 %0, %1, %2, %3" : "=v"(d) : "v"(c), "v"(m), "v"(a))

// ---------------------------------------------------------------------------
// Fused kernel: phase 1 computes this block's chunk of per-gaussian polynomial
// coefficients straight into LDS (pair-interleaved); phase 2 evaluates
// 1024 points x 256 gaussians with packed (2-gaussian) math.
//
// Per-gaussian coefficients (c = 0.5*log2e), so alpha = w * exp2(poly(p)):
//   [0..2] = -c*G00, -c*G11, -c*G22
//   [3..5] = -2c*G01, -2c*G02, -2c*G12
//   [6..8] = h = 2c*G*mu
//   [9]    = k0 = -(h.mu)/2
//   [10]   = w,  [11] = w*v
// LDS layout: lc[pair][6] of float4; float element (pair, k, half):
//   ((float*)lc)[pair*24 + 2*k + half]
// so one b128 read gives two f32x2 coefficient pairs.
// ---------------------------------------------------------------------------
__global__ __launch_bounds__(BLK, 4) void vegs_fused(
    const float* __restrict__ x,
    const float* __restrict__ xyz,
    const float* __restrict__ weight_raw,
    const float* __restrict__ scaling_raw,
    const float* __restrict__ rotation_raw,
    const float* __restrict__ values_raw,
    float2* __restrict__ partial)
{
    __shared__ f32x4 lc[CHUNK / 2][6];

    const int t  = threadIdx.x;
    const int cb = blockIdx.y;            // chunk index
    const int n  = cb * CHUNK + t;        // this thread's gaussian

    // ---------------- phase 1: coefficients -> LDS ----------------
    {
        float s0 = fast_exp(scaling_raw[n * 3 + 0]);
        float s1 = fast_exp(scaling_raw[n * 3 + 1]);
        float s2 = fast_exp(scaling_raw[n * 3 + 2]);
        float r = sqrtf(s0 * s0 + s1 * s1 + s2 * s2) + 1e-8f;
        // tanh(y) = (E-1)/(E+1), E = exp(2y)
        float y = r * (1.0f / MAX_SCALE);
        float E = fast_exp2(2.0f * LOG2E * y);
        float th = (E - 1.0f) * fast_rcp(E + 1.0f);
        float k = (MAX_SCALE * th) * fast_rcp(r);   // r_soft / r
        s0 *= k; s1 *= k; s2 *= k;

        float i0 = fast_rcp(s0 * s0);
        float i1 = fast_rcp(s1 * s1);
        float i2 = fast_rcp(s2 * s2);

        float qw = rotation_raw[n * 4 + 0];
        float qx = rotation_raw[n * 4 + 1];
        float qy = rotation_raw[n * 4 + 2];
        float qz = rotation_raw[n * 4 + 3];
        float qn = sqrtf(qw * qw + qx * qx + qy * qy + qz * qz) + 1e-12f;
        float iq = fast_rcp(qn);
        qw *= iq; qx *= iq; qy *= iq; qz *= iq;

        float r00 = 1.0f - 2.0f * (qy * qy + qz * qz);
        float r01 = 2.0f * (qx * qy - qw * qz);
        float r02 = 2.0f * (qx * qz + qw * qy);
        float r10 = 2.0f * (qx * qy + qw * qz);
        float r11 = 1.0f - 2.0f * (qx * qx + qz * qz);
        float r12 = 2.0f * (qy * qz - qw * qx);
        float r20 = 2.0f * (qx * qz - qw * qy);
        float r21 = 2.0f * (qy * qz + qw * qx);
        float r22 = 1.0f - 2.0f * (qx * qx + qy * qy);

        float G00 = r00 * r00 * i0 + r01 * r01 * i1 + r02 * r02 * i2;
        float G11 = r10 * r10 * i0 + r11 * r11 * i1 + r12 * r12 * i2;
        float G22 = r20 * r20 * i0 + r21 * r21 * i1 + r22 * r22 * i2;
        float G01 = r00 * r10 * i0 + r01 * r11 * i1 + r02 * r12 * i2;
        float G02 = r00 * r20 * i0 + r01 * r21 * i1 + r02 * r22 * i2;
        float G12 = r10 * r20 * i0 + r11 * r21 * i1 + r12 * r22 * i2;

        float w  = fast_sigmoid(weight_raw[n]);
        float v  = fast_sigmoid(values_raw[n]);
        float m0 = xyz[n * 3 + 0];
        float m1 = xyz[n * 3 + 1];
        float m2 = xyz[n * 3 + 2];

        const float c = HALF_LOG2E;
        float h0 = 2.0f * c * (G00 * m0 + G01 * m1 + G02 * m2);
        float h1 = 2.0f * c * (G01 * m0 + G11 * m1 + G12 * m2);
        float h2 = 2.0f * c * (G02 * m0 + G12 * m1 + G22 * m2);
        float k0 = -0.5f * (h0 * m0 + h1 * m1 + h2 * m2);

        float cf[12] = { -c * G00, -c * G11, -c * G22,
                         -2.0f * c * G01, -2.0f * c * G02, -2.0f * c * G12,
                         h0, h1, h2, k0, w, w * v };
        float* lf = (float*)lc;
        const int base = (t >> 1) * 24 + (t & 1);
        #pragma unroll
        for (int kk = 0; kk < 12; ++kk) lf[base + 2 * kk] = cf[kk];
    }

    // point coords + splat pairs (p = (x+1)/2); Horner form needs only p0,p1,p2.
    const int m0i = blockIdx.x * PT_PER_BLK + t;
    f32x2 sp[PPT][3];
    #pragma unroll
    for (int i = 0; i < PPT; ++i) {
        int m = m0i + i * BLK;
        #pragma unroll
        for (int j = 0; j < 3; ++j) {
            float p = (x[m * 3 + j] + 1.0f) * 0.5f;
            sp[i][j].x = p; sp[i][j].y = p;
        }
    }

    f32x2 accN[PPT], accD[PPT];
    #pragma unroll
    for (int i = 0; i < PPT; ++i) { accN[i] = (f32x2)0.0f; accD[i] = (f32x2)0.0f; }

    __syncthreads();

    // ---------------- phase 2: main loop over gaussian pairs ----------------
    #pragma unroll 2
    for (int jp = 0; jp < CHUNK / 2; ++jp) {
        f32x4 F0 = lc[jp][0];
        f32x4 F1 = lc[jp][1];
        f32x4 F2 = lc[jp][2];
        f32x4 F3 = lc[jp][3];
        f32x4 F4 = lc[jp][4];
        f32x4 F5 = lc[jp][5];
        f32x2 K0 = F0.xy, K1 = F0.zw;    // -cG00, -cG11
        f32x2 K2 = F1.xy, K3 = F1.zw;    // -cG22, -2cG01
        f32x2 K4 = F2.xy, K5 = F2.zw;    // -2cG02, -2cG12
        f32x2 K6 = F3.xy, K7 = F3.zw;    // h0, h1
        f32x2 K8 = F4.xy, K9 = F4.zw;    // h2, k0
        f32x2 KW = F5.xy, KV = F5.zw;    // w, w*v

        #pragma unroll
        for (int i = 0; i < PPT; ++i) {
            // Horner: q = k0 + p0*(h0 + c00 p0 + c01 p1 + c02 p2)
            //             + p1*(h1 + c11 p1 + c12 p2) + p2*(h2 + c22 p2)
            f32x2 t0, t1, t2, q;
            PK_FMA3(t0, K0, sp[i][0], K6);
            PK_FMA (t0, K3, sp[i][1]);
            PK_FMA (t0, K4, sp[i][2]);
            PK_FMA3(t1, K1, sp[i][1], K7);
            PK_FMA (t1, K5, sp[i][2]);
            PK_FMA3(t2, K2, sp[i][2], K8);
            PK_FMA3(q, sp[i][0], t0, K9);
            PK_FMA (q, sp[i][1], t1);
            PK_FMA (q, sp[i][2], t2);
            f32x2 e;
            e.x = fast_exp2(q.x);
            e.y = fast_exp2(q.y);
            PK_FMA(accD[i], KW, e);
            PK_FMA(accN[i], KV, e);
        }
    }

    #pragma unroll
    for (int i = 0; i < PPT; ++i) {
        partial[(size_t)cb * MP + m0i + i * BLK] =
            make_float2(accN[i].x + accN[i].y, accD[i].x + accD[i].y);
    }
}

// ---------------------------------------------------------------------------
// Reduce: 128 blocks x 256 threads; 4 threads per point (chunk slices),
// coalesced reads, LDS combine, background select.
// ---------------------------------------------------------------------------
__global__ __launch_bounds__(256) void vegs_reduce(
    const float2* __restrict__ partial,
    float* __restrict__ out)
{
    __shared__ float2 red[256];
    const int t = threadIdx.x;
    const int m = blockIdx.x * 64 + (t & 63);
    const int s = t >> 6;                       // slice 0..3
    constexpr int PER = NCHUNK / 4;             // 32

    float num = 0.0f, den = 0.0f;
    #pragma unroll 8
    for (int k = 0; k < PER; ++k) {
        float2 p = partial[(size_t)(s * PER + k) * MP + m];
        num += p.x;
        den += p.y;
    }
    red[t] = make_float2(num, den);
    __syncthreads();
    if (t < 64) {
        float2 r0 = red[t], r1 = red[t + 64], r2 = red[t + 128], r3 = red[t + 192];
        float nn = r0.x + r1.x + r2.x + r3.x;
        float dd = r0.y + r1.y + r2.y + r3.y;
        out[m] = (dd > 1e-8f) ? nn : BG_VAL;
    }
}

extern "C" void kernel_launch(void* const* d_in, const int* in_sizes, int n_in,
                              void* d_out, int out_size, void* d_ws, size_t ws_size,
                              hipStream_t stream) {
    const float* x            = (const float*)d_in[0];
    const float* xyz          = (const float*)d_in[1];
    const float* weight_raw   = (const float*)d_in[2];
    const float* scaling_raw  = (const float*)d_in[3];
    const float* rotation_raw = (const float*)d_in[4];
    const float* values_raw   = (const float*)d_in[5];
    float* out = (float*)d_out;

    float2* partial = (float2*)d_ws;    // NCHUNK * MP * 8 B = 8 MB

    dim3 grid(PT_TILES, NCHUNK);        // (8, 128) = 1024 blocks, 4/CU resident
    vegs_fused<<<grid, BLK, 0, stream>>>(
        x, xyz, weight_raw, scaling_raw, rotation_raw, values_raw, partial);

    vegs_reduce<<<MP / 64, 256, 0, stream>>>(partial, out);
}